// Round 4
// baseline (257.494 us; speedup 1.0000x reference)
//
#include <hip/hip_runtime.h>
#include <hip/hip_bf16.h>

#define QN 4096
#define CN 4096
#define DN 1024
#define EPSV 1e-6f

#define BM 128
#define BN 128
#define BK 32
#define TILE (BM * BK)          // 4096 bf16 elems = 8 KB per staged tile

#define MATSZ ((size_t)QN * DN)

using bf16x8 = __attribute__((ext_vector_type(8))) __bf16;
using f32x4  = __attribute__((ext_vector_type(4))) float;

static __device__ __forceinline__ unsigned short f2bf_rne(float x) {
  unsigned int u = __float_as_uint(x);
  unsigned int r = (u + 0x7FFFu + ((u >> 16) & 1u)) >> 16;
  return (unsigned short)r;
}
static __device__ __forceinline__ float bf2f(unsigned short h) {
  return __uint_as_float(((unsigned int)h) << 16);
}

// async global->LDS, 16B per lane; LDS dest is wave-uniform base + lane*16
static __device__ __forceinline__ void gload_lds16(const unsigned short* g, unsigned short* l) {
  __builtin_amdgcn_global_load_lds(
      (const __attribute__((address_space(1))) unsigned int*)g,
      (__attribute__((address_space(3))) unsigned int*)l, 16, 0, 0);
}

// ws16 layout (ushort elems): 0:t_rgb | 1:t_flow | 2:c_rgb | 3:c_flow (bf16-rounded)
// then norms (float): tn_r[QN], tn_f[QN], cn_r[CN], cn_f[CN]

__global__ void prep_kernel(const float* __restrict__ tgt_r, const float* __restrict__ tgt_f,
                            const float* __restrict__ ctx_r, const float* __restrict__ ctx_f,
                            unsigned short* __restrict__ ws16, float* __restrict__ norms) {
  const int row = blockIdx.x;
  const int mat = blockIdx.y;
  const int t = threadIdx.x;
  const float* src; float eps;
  switch (mat) {
    case 0:  src = tgt_r; eps = EPSV; break;
    case 1:  src = tgt_f; eps = EPSV; break;
    case 2:  src = ctx_r; eps = 0.f;  break;
    default: src = ctx_f; eps = 0.f;  break;
  }
  unsigned short* hi = ws16 + (size_t)mat * MATSZ;
  float* nrm = norms + (size_t)mat * QN;
  const size_t base = (size_t)row * DN;
  float4 v = ((const float4*)(src + base))[t];
  float a[4] = {v.x + eps, v.y + eps, v.z + eps, v.w + eps};
  float ss = 0.f;
  unsigned short hh[4];
#pragma unroll
  for (int k = 0; k < 4; ++k) {
    hh[k] = f2bf_rne(a[k]);
    float f = bf2f(hh[k]);         // norm of the rounded value (consistency)
    ss += f * f;
  }
  ((ushort4*)(hi + base))[t] = make_ushort4(hh[0], hh[1], hh[2], hh[3]);

#pragma unroll
  for (int o = 32; o > 0; o >>= 1) ss += __shfl_down(ss, o);
  __shared__ float red[4];
  if ((t & 63) == 0) red[t >> 6] = ss;
  __syncthreads();
  if (t == 0) nrm[row] = red[0] + red[1] + red[2] + red[3];
}

// Producer-consumer dual bf16 GEMM + distance/exp epilogue.
// 512 threads: waves 0-3 = consumers (2x2, each 64x64 per modality, dual-mod
// acc), waves 4-7 = producers (one tile each: Ar/Af/Br/Bf). LDS double-buffer
// (2 x 32 KB), ONE barrier per K-chunk: producers issue next-buffer
// global_load_lds right after the barrier, and their compiler-emitted
// vmcnt(0) drain overlaps the consumers' MFMA phase -- consumer waves never
// carry outstanding vmcnt, so they cross barriers without memory stalls.
// LDS swizzle: two 64B tile-rows packed per 128B LDS line, 16B-chunk position
// XORed with (line&7)  ->  8-start-bank spread (round-3-proven, 0 conflicts).
__global__ __launch_bounds__(512, 2)
void gemm_kernel(const unsigned short* __restrict__ ws16,
                 const float* __restrict__ norms,
                 const float* __restrict__ c_r, const float* __restrict__ c_f,
                 float* __restrict__ out) {
  __shared__ unsigned short S[2][4 * TILE];   // [buf][Ar|Af|Br|Bf], 64 KB total

  const int t = threadIdx.x;
  const int lane = t & 63;
  const int wid = t >> 6;
  const int row0 = blockIdx.y * BM;   // target rows
  const int col0 = blockIdx.x * BN;   // context cols

  if (wid >= 4) {
    // ---------------- producer ----------------
    const int tl = wid - 4;           // tile: 0=Ar 1=Af 2=Br 3=Bf
    const unsigned short* base = ws16 + (size_t)tl * MATSZ
                               + (size_t)(tl < 2 ? row0 : col0) * DN;
    // lane -> LDS (line, pos): line = l>>3 (rel), pos = l&7.
    // stored pos p holds original pos p^(line&7); orig pos -> (rowpair, chunk)
    const int po = (lane & 7) ^ (lane >> 3);
    const int r0 = 2 * (lane >> 3) + (po >> 2);   // source row within 16-row strip
    const int c0 = (po & 3) * 8;                  // source col offset (elems)
    const unsigned short* src = base + (size_t)r0 * DN + c0;
    unsigned short* dst0 = &S[0][tl * TILE];

    // prologue: stage kc=0 into buf 0 (8 wave-loads of 16 rows each)
#pragma unroll
    for (int i = 0; i < 8; ++i)
      gload_lds16(src + (size_t)i * 16 * DN, dst0 + i * 512);

    for (int kc = 0; kc < DN / BK; ++kc) {
      __syncthreads();    // buf[kc&1] drained (we waited vmcnt before entry)
      if (kc + 1 < DN / BK) {
        const unsigned short* s2 = src + (kc + 1) * BK;
        unsigned short* d2 = &S[(kc + 1) & 1][tl * TILE];
#pragma unroll
        for (int i = 0; i < 8; ++i)
          gload_lds16(s2 + (size_t)i * 16 * DN, d2 + i * 512);
      }
    }
    return;   // producers done; consumers have no further barriers
  }

  // ---------------- consumer ----------------
  const int wr = wid >> 1;
  const int wc = wid & 1;

  f32x4 acc[2][4][4];
#pragma unroll
  for (int m = 0; m < 2; ++m)
#pragma unroll
    for (int i = 0; i < 4; ++i)
#pragma unroll
      for (int j = 0; j < 4; ++j)
        acc[m][i][j] = (f32x4){0.f, 0.f, 0.f, 0.f};

  // frag read offsets: row R = w*64 + i*16 + lr, k-chunk lq.
  // line = R>>1, pos = (lq + 4*(R&1)) ^ ((R>>1)&7); (R>>1)&7 == lr>>1
  const int lr = lane & 15;
  const int lq = lane >> 4;
  const int pos = (lq + 4 * (lr & 1)) ^ (lr >> 1);
  int ra[4], rb[4];
#pragma unroll
  for (int i = 0; i < 4; ++i) {
    ra[i] = (wr * 32 + i * 8 + (lr >> 1)) * 64 + pos * 8;
    rb[i] = (wc * 32 + i * 8 + (lr >> 1)) * 64 + pos * 8;
  }

  for (int kc = 0; kc < DN / BK; ++kc) {
    __syncthreads();    // buf[kc&1] ready
    const unsigned short* Sb = &S[kc & 1][0];
    bf16x8 ar[4], af[4], br[4], bf[4];
#pragma unroll
    for (int i = 0; i < 4; ++i) {
      ar[i] = *(const bf16x8*)(Sb + 0 * TILE + ra[i]);
      af[i] = *(const bf16x8*)(Sb + 1 * TILE + ra[i]);
      br[i] = *(const bf16x8*)(Sb + 2 * TILE + rb[i]);
      bf[i] = *(const bf16x8*)(Sb + 3 * TILE + rb[i]);
    }
#pragma unroll
    for (int i = 0; i < 4; ++i)
#pragma unroll
      for (int j = 0; j < 4; ++j) {
        acc[0][i][j] = __builtin_amdgcn_mfma_f32_16x16x32_bf16(ar[i], br[j], acc[0][i][j], 0, 0, 0);
        acc[1][i][j] = __builtin_amdgcn_mfma_f32_16x16x32_bf16(af[i], bf[j], acc[1][i][j], 0, 0, 0);
      }
  }

  // epilogue: sq = ||t||^2 + ||c||^2 - 2*dot ; p = w_r*exp(-d_r) + w_f*exp(-d_f)
  const float* tn_r = norms;
  const float* tn_f = norms + QN;
  const float* cn_r = norms + 2 * QN;
  const float* cn_f = norms + 3 * QN;

#pragma unroll
  for (int i = 0; i < 4; ++i) {
#pragma unroll
    for (int r = 0; r < 4; ++r) {
      const int tq = row0 + wr * 64 + i * 16 + lq * 4 + r;   // C/D row = (lane>>4)*4 + reg
      const float tnr = tn_r[tq];
      const float tnf = tn_f[tq];
      const float cr = c_r[tq], cf = c_f[tq];
      const float inv = 1.f / (cr + cf);
      const float wgr = cr * inv, wgf = cf * inv;
#pragma unroll
      for (int j = 0; j < 4; ++j) {
        const int cc = col0 + wc * 64 + j * 16 + lr;          // C/D col = lane&15
        const float sr_ = tnr + cn_r[cc] - 2.f * acc[0][i][j][r];
        const float sf_ = tnf + cn_f[cc] - 2.f * acc[1][i][j][r];
        const float dr = sqrtf(fmaxf(sr_, 0.f));
        const float df = sqrtf(fmaxf(sf_, 0.f));
        const float p = wgr * __expf(-dr) + wgf * __expf(-df);
        out[(size_t)tq * CN + cc] = p;
      }
    }
  }
}

// Per-row sum + normalize, in place. Deterministic (no atomics).
__global__ void norm_kernel(float* __restrict__ out) {
  const int row = blockIdx.x;
  const int t = threadIdx.x;
  float4* p = (float4*)(out + (size_t)row * CN);
  float4 v[4];
  float s = 0.f;
#pragma unroll
  for (int i = 0; i < 4; ++i) {
    v[i] = p[t + 256 * i];
    s += v[i].x + v[i].y + v[i].z + v[i].w;
  }
#pragma unroll
  for (int o = 32; o > 0; o >>= 1) s += __shfl_down(s, o);
  __shared__ float red[4];
  if ((t & 63) == 0) red[t >> 6] = s;
  __syncthreads();
  const float inv = 1.f / (red[0] + red[1] + red[2] + red[3]);
#pragma unroll
  for (int i = 0; i < 4; ++i) {
    v[i].x *= inv; v[i].y *= inv; v[i].z *= inv; v[i].w *= inv;
    p[t + 256 * i] = v[i];
  }
}

extern "C" void kernel_launch(void* const* d_in, const int* in_sizes, int n_in,
                              void* d_out, int out_size, void* d_ws, size_t ws_size,
                              hipStream_t stream) {
  const float* ctx_r = (const float*)d_in[0];
  const float* ctx_f = (const float*)d_in[1];
  const float* tgt_r = (const float*)d_in[2];
  const float* tgt_f = (const float*)d_in[3];
  const float* c_r   = (const float*)d_in[4];
  const float* c_f   = (const float*)d_in[5];
  float* out = (float*)d_out;
  unsigned short* ws16 = (unsigned short*)d_ws;
  float* norms = (float*)(ws16 + 4 * MATSZ);

  prep_kernel<<<dim3(QN, 4), 256, 0, stream>>>(tgt_r, tgt_f, ctx_r, ctx_f, ws16, norms);
  gemm_kernel<<<dim3(CN / BN, QN / BM), 512, 0, stream>>>(ws16, norms, c_r, c_f, out);
  norm_kernel<<<QN, 256, 0, stream>>>(out);
}

// Round 5
// 242.719 us; speedup vs baseline: 1.0609x; 1.0609x over previous
//
#include <hip/hip_runtime.h>
#include <hip/hip_bf16.h>

#define QN 4096
#define CN 4096
#define DN 1024
#define EPSV 1e-6f

#define BM 128
#define BN 128
#define BK 64
#define TILE (BM * BK)          // 8192 bf16 elems = 16 KB per staged tile

#define MATSZ ((size_t)QN * DN)

using bf16x8 = __attribute__((ext_vector_type(8))) __bf16;
using f32x4  = __attribute__((ext_vector_type(4))) float;

static __device__ __forceinline__ unsigned short f2bf_rne(float x) {
  unsigned int u = __float_as_uint(x);
  unsigned int r = (u + 0x7FFFu + ((u >> 16) & 1u)) >> 16;
  return (unsigned short)r;
}
static __device__ __forceinline__ float bf2f(unsigned short h) {
  return __uint_as_float(((unsigned int)h) << 16);
}

// async global->LDS, 16B per lane; LDS dest is wave-uniform base + lane*16
static __device__ __forceinline__ void gload_lds16(const unsigned short* g, unsigned short* l) {
  __builtin_amdgcn_global_load_lds(
      (const __attribute__((address_space(1))) unsigned int*)g,
      (__attribute__((address_space(3))) unsigned int*)l, 16, 0, 0);
}

// ws16 layout (ushort elems): 0:t_rgb | 1:t_flow | 2:c_rgb | 3:c_flow (bf16-rounded)
// then norms (float): tn_r[QN], tn_f[QN], cn_r[CN], cn_f[CN]

__global__ void prep_kernel(const float* __restrict__ tgt_r, const float* __restrict__ tgt_f,
                            const float* __restrict__ ctx_r, const float* __restrict__ ctx_f,
                            unsigned short* __restrict__ ws16, float* __restrict__ norms) {
  const int row = blockIdx.x;
  const int mat = blockIdx.y;
  const int t = threadIdx.x;
  const float* src; float eps;
  switch (mat) {
    case 0:  src = tgt_r; eps = EPSV; break;
    case 1:  src = tgt_f; eps = EPSV; break;
    case 2:  src = ctx_r; eps = 0.f;  break;
    default: src = ctx_f; eps = 0.f;  break;
  }
  unsigned short* hi = ws16 + (size_t)mat * MATSZ;
  float* nrm = norms + (size_t)mat * QN;
  const size_t base = (size_t)row * DN;
  float4 v = ((const float4*)(src + base))[t];
  float a[4] = {v.x + eps, v.y + eps, v.z + eps, v.w + eps};
  float ss = 0.f;
  unsigned short hh[4];
#pragma unroll
  for (int k = 0; k < 4; ++k) {
    hh[k] = f2bf_rne(a[k]);
    float f = bf2f(hh[k]);         // norm of the rounded value (consistency)
    ss += f * f;
  }
  ((ushort4*)(hi + base))[t] = make_ushort4(hh[0], hh[1], hh[2], hh[3]);

#pragma unroll
  for (int o = 32; o > 0; o >>= 1) ss += __shfl_down(ss, o);
  __shared__ float red[4];
  if ((t & 63) == 0) red[t >> 6] = ss;
  __syncthreads();
  if (t == 0) nrm[row] = red[0] + red[1] + red[2] + red[3];
}

// Producer-consumer dual bf16 GEMM + distance/exp epilogue.
// 512 threads: waves 0-3 consumers (2x2, each 64x64; acc[phase]), waves 4-7
// producers. K-sweep is MODALITY-PHASED: phase 0 stages/computes rgb over all
// of K, phase 1 flow. Per buffer: {A,B} of one modality at BK=64 -> every
// global_load_lds reads a full 128B line per row (fixes round 4's half-line
// double-fetch; FETCH 98.9 -> ~82 MB predicted). Double-buffer = 64 KB static.
// One barrier per iteration; producers stage it+1 right after barrier it, so
// their vmcnt drain overlaps the consumers' MFMA phase.
// LDS swizzle: 8 chunks of 16B per 128B row, chunk XORed with (row&7)
// (round-3-proven, 0 bank conflicts).
// Grid swizzle (b%8 = XCD): xcd owns a 4-wide B column band (L2-resident,
// ~2 MB/phase); 4 consecutive s share the A-tile (y) for L2 A-reuse.
__global__ __launch_bounds__(512, 2)
void gemm_kernel(const unsigned short* __restrict__ ws16,
                 const float* __restrict__ norms,
                 const float* __restrict__ c_r, const float* __restrict__ c_f,
                 float* __restrict__ out) {
  __shared__ unsigned short S[2][2][TILE];   // [buf][A|B][128x64 swizzled] = 64 KB

  const int t = threadIdx.x;
  const int lane = t & 63;
  const int wid = t >> 6;

  // XCD-aware block swizzle: x = (b&7)*4 + ((b>>3)&3), y = b>>5
  const int b = blockIdx.x;
  const int row0 = (b >> 5) * BM;                       // target rows (A / y)
  const int col0 = (((b & 7) << 2) | ((b >> 3) & 3)) * BN;  // context cols (B / x)

  if (wid >= 4) {
    // ---------------- producer ----------------
    const int pw = wid - 4;
    const int tl = pw >> 1;          // 0 = A (targets), 1 = B (contexts)
    const int half = pw & 1;         // 64-row half of the 128-row tile
    const int srw = lane >> 3;               // row-in-8 (== row&7 of tile row)
    const int sch = (lane & 7) ^ srw;        // swizzled source 16B-chunk
    const size_t rbase = (size_t)((tl ? col0 : row0) + half * 64) * DN;
    // matrix index: A: phase (0=t_rgb,1=t_flow); B: 2+phase
    const unsigned short* m0 = ws16 + (size_t)(tl * 2) * MATSZ + rbase
                             + (size_t)srw * DN + sch * 8;
    unsigned short* d0 = &S[0][tl][half * 64 * BK];

    // stage iteration 'it' into buf it&1  (phase = it>>4, kc = it&15)
#define STAGE(it)                                                            \
    {                                                                        \
      const int ph = (it) >> 4;                                              \
      const unsigned short* sP = m0 + (size_t)ph * MATSZ + ((it) & 15) * BK; \
      unsigned short* dP = d0 + ((it) & 1) * (2 * TILE);                     \
      _Pragma("unroll")                                                      \
      for (int i = 0; i < 8; ++i)                                            \
        gload_lds16(sP + (size_t)i * 8 * DN, dP + i * 512);                  \
    }

    STAGE(0);
    for (int it = 0; it < 32; ++it) {
      __syncthreads();
      if (it < 31) STAGE(it + 1);
    }
    return;
  }

  // ---------------- consumer ----------------
  const int wr = wid >> 1;
  const int wc = wid & 1;

  f32x4 acc[2][4][4];
#pragma unroll
  for (int m = 0; m < 2; ++m)
#pragma unroll
    for (int i = 0; i < 4; ++i)
#pragma unroll
      for (int j = 0; j < 4; ++j)
        acc[m][i][j] = (f32x4){0.f, 0.f, 0.f, 0.f};

  // frag offsets (elems, row stride 64): row R, ksub0 chunk lq ^ (R&7)
  const int lr = lane & 15;
  const int lq = lane >> 4;
  const int sc0 = (lq ^ (lr & 7)) * 8;
  int ra[4], rb[4];
#pragma unroll
  for (int i = 0; i < 4; ++i) {
    ra[i] = (wr * 64 + i * 16 + lr) * BK + sc0;
    rb[i] = (wc * 64 + i * 16 + lr) * BK + sc0;
  }
#define KS1(x) ((x) ^ 32)   // ksub1: chunk (lq+4)^(R&7) -> xor 32 elems

#pragma unroll
  for (int phase = 0; phase < 2; ++phase) {
    for (int kc = 0; kc < 16; ++kc) {
      __syncthreads();    // buf ready
      const unsigned short* Sa = &S[(phase * 16 + kc) & 1][0][0];
      const unsigned short* Sb = &S[(phase * 16 + kc) & 1][1][0];
      bf16x8 a0[4], a1[4], b0[4], b1[4];
#pragma unroll
      for (int i = 0; i < 4; ++i) {
        a0[i] = *(const bf16x8*)(Sa + ra[i]);
        a1[i] = *(const bf16x8*)(Sa + KS1(ra[i]));
        b0[i] = *(const bf16x8*)(Sb + rb[i]);
        b1[i] = *(const bf16x8*)(Sb + KS1(rb[i]));
      }
#pragma unroll
      for (int i = 0; i < 4; ++i)
#pragma unroll
        for (int j = 0; j < 4; ++j) {
          acc[phase][i][j] = __builtin_amdgcn_mfma_f32_16x16x32_bf16(a0[i], b0[j], acc[phase][i][j], 0, 0, 0);
          acc[phase][i][j] = __builtin_amdgcn_mfma_f32_16x16x32_bf16(a1[i], b1[j], acc[phase][i][j], 0, 0, 0);
        }
    }
  }

  // epilogue: sq = ||t||^2 + ||c||^2 - 2*dot ; p = w_r*exp(-d_r) + w_f*exp(-d_f)
  const float* tn_r = norms;
  const float* tn_f = norms + QN;
  const float* cn_r = norms + 2 * QN;
  const float* cn_f = norms + 3 * QN;

#pragma unroll
  for (int i = 0; i < 4; ++i) {
#pragma unroll
    for (int r = 0; r < 4; ++r) {
      const int tq = row0 + wr * 64 + i * 16 + lq * 4 + r;   // C/D row = (lane>>4)*4 + reg
      const float tnr = tn_r[tq];
      const float tnf = tn_f[tq];
      const float cr = c_r[tq], cf = c_f[tq];
      const float inv = 1.f / (cr + cf);
      const float wgr = cr * inv, wgf = cf * inv;
#pragma unroll
      for (int j = 0; j < 4; ++j) {
        const int cc = col0 + wc * 64 + j * 16 + lr;          // C/D col = lane&15
        const float sr_ = tnr + cn_r[cc] - 2.f * acc[0][i][j][r];
        const float sf_ = tnf + cn_f[cc] - 2.f * acc[1][i][j][r];
        const float dr = sqrtf(fmaxf(sr_, 0.f));
        const float df = sqrtf(fmaxf(sf_, 0.f));
        const float p = wgr * __expf(-dr) + wgf * __expf(-df);
        out[(size_t)tq * CN + cc] = p;
      }
    }
  }
}

// Per-row sum + normalize, in place. Deterministic (no atomics).
__global__ void norm_kernel(float* __restrict__ out) {
  const int row = blockIdx.x;
  const int t = threadIdx.x;
  float4* p = (float4*)(out + (size_t)row * CN);
  float4 v[4];
  float s = 0.f;
#pragma unroll
  for (int i = 0; i < 4; ++i) {
    v[i] = p[t + 256 * i];
    s += v[i].x + v[i].y + v[i].z + v[i].w;
  }
#pragma unroll
  for (int o = 32; o > 0; o >>= 1) s += __shfl_down(s, o);
  __shared__ float red[4];
  if ((t & 63) == 0) red[t >> 6] = s;
  __syncthreads();
  const float inv = 1.f / (red[0] + red[1] + red[2] + red[3]);
#pragma unroll
  for (int i = 0; i < 4; ++i) {
    v[i].x *= inv; v[i].y *= inv; v[i].z *= inv; v[i].w *= inv;
    p[t + 256 * i] = v[i];
  }
}

extern "C" void kernel_launch(void* const* d_in, const int* in_sizes, int n_in,
                              void* d_out, int out_size, void* d_ws, size_t ws_size,
                              hipStream_t stream) {
  const float* ctx_r = (const float*)d_in[0];
  const float* ctx_f = (const float*)d_in[1];
  const float* tgt_r = (const float*)d_in[2];
  const float* tgt_f = (const float*)d_in[3];
  const float* c_r   = (const float*)d_in[4];
  const float* c_f   = (const float*)d_in[5];
  float* out = (float*)d_out;
  unsigned short* ws16 = (unsigned short*)d_ws;
  float* norms = (float*)(ws16 + 4 * MATSZ);

  prep_kernel<<<dim3(QN, 4), 256, 0, stream>>>(tgt_r, tgt_f, ctx_r, ctx_f, ws16, norms);
  gemm_kernel<<<dim3(1024), 512, 0, stream>>>(ws16, norms, c_r, c_f, out);
  norm_kernel<<<QN, 256, 0, stream>>>(out);
}